// Round 7
// baseline (267.889 us; speedup 1.0000x reference)
//
#include <hip/hip_runtime.h>
#include <hip/hip_fp16.h>
#include <math.h>

// ChebConv (K=4) GNN head. N=50000, E=800000, F_IN=64, H=128.
// R7: one-row-per-wave SPMM (64 lanes = 8 edges x 8 chunks per gather instr,
// 50k waves for max TLP), weight-free via pre-scaled rows, col-only 4-pass
// scatter, MFMA GEMM.

#define FIN 64
#define HDIM 128

typedef _Float16 half8 __attribute__((ext_vector_type(8)));
typedef float f32x4 __attribute__((ext_vector_type(4)));

union U16 { uint4 u; __half2 h2[4]; half8 h8; };

__global__ void count_deg(const int* __restrict__ row, int* __restrict__ deg, int E) {
    int e = blockIdx.x * blockDim.x + threadIdx.x;
    if (e < E) atomicAdd(&deg[row[e]], 1);
}

__global__ void make_dinv(const int* __restrict__ deg, float* __restrict__ dinv, int n) {
    int i = blockIdx.x * blockDim.x + threadIdx.x;
    if (i < n) {
        int d = deg[i];
        dinv[i] = (d > 0) ? rsqrtf((float)d) : 0.f;
    }
}

// features fp32 -> fp16 rows: unscaled (dsth, GEMM/prev) + dinv-scaled (dsts,
// gather source).
__global__ void cvt_feat(const float4* __restrict__ src, const float* __restrict__ dinv,
                         uint4* __restrict__ dsth, uint4* __restrict__ dsts, int n8) {
    int i = blockIdx.x * blockDim.x + threadIdx.x;
    if (i >= n8) return;
    float d = dinv[i >> 3];
    float4 a = src[i * 2], b = src[i * 2 + 1];
    U16 v, vs;
    v.h2[0] = __float22half2_rn(make_float2(a.x, a.y));
    v.h2[1] = __float22half2_rn(make_float2(a.z, a.w));
    v.h2[2] = __float22half2_rn(make_float2(b.x, b.y));
    v.h2[3] = __float22half2_rn(make_float2(b.z, b.w));
    vs.h2[0] = __float22half2_rn(make_float2(d * a.x, d * a.y));
    vs.h2[1] = __float22half2_rn(make_float2(d * a.z, d * a.w));
    vs.h2[2] = __float22half2_rn(make_float2(d * b.x, d * b.y));
    vs.h2[3] = __float22half2_rn(make_float2(d * b.z, d * b.w));
    dsth[i] = v.u;
    dsts[i] = vs.u;
}

// Pre-swizzle cheb_w (B[256 k][128 h] fp32) into per-lane MFMA B-fragments.
__global__ void make_bfrag(const float* __restrict__ W, uint4* __restrict__ bfrag) {
    int t = blockIdx.x * blockDim.x + threadIdx.x;   // 0..4095
    if (t >= 8 * 8 * 64) return;
    int lane = t & 63;
    int ht = (t >> 6) & 7;
    int kk = t >> 9;
    int h = ht * 16 + (lane & 15);
    int kb = kk * 32 + (lane >> 4) * 8;
    U16 v;
#pragma unroll
    for (int j = 0; j < 4; ++j) {
        float a = W[(kb + 2 * j) * HDIM + h];
        float b = W[(kb + 2 * j + 1) * HDIM + h];
        v.h2[j] = __float22half2_rn(make_float2(a, b));
    }
    bfrag[t] = v.u;
}

// Per-block exclusive scan (Hillis-Steele over 1024 elems) + block totals.
__global__ void scan_local(const int* __restrict__ in, int* __restrict__ out,
                           int* __restrict__ bsum, int n) {
    __shared__ int buf[1024];
    int tid = threadIdx.x;
    int gid = blockIdx.x * 1024 + tid;
    int v = (gid < n) ? in[gid] : 0;
    int x = v;
    buf[tid] = x;
    __syncthreads();
    for (int off = 1; off < 1024; off <<= 1) {
        int t = (tid >= off) ? buf[tid - off] : 0;
        __syncthreads();
        x += t;
        buf[tid] = x;
        __syncthreads();
    }
    if (gid < n) out[gid] = x - v;
    if (tid == 1023) bsum[blockIdx.x] = x;
}

__global__ void scan_bsums(int* bsum, int nb) {
    if (blockIdx.x == 0 && threadIdx.x == 0) {
        int acc = 0;
        for (int b = 0; b < nb; ++b) { int t = bsum[b]; bsum[b] = acc; acc += t; }
    }
}

__global__ void scan_finish(int* __restrict__ rowptr, const int* __restrict__ bsum,
                            int* __restrict__ cursor, int n, int E) {
    int i = blockIdx.x * blockDim.x + threadIdx.x;
    if (i < n) {
        int v = rowptr[i] + bsum[i >> 10];
        rowptr[i] = v;
        cursor[i] = v;
    } else if (i == n) {
        rowptr[n] = E;
    }
}

// Row-striped scatter pass: only rows in [r_lo, r_hi) are placed, so the
// write window (their CSR span) + cursors stay L2-resident.
__global__ void scatter_pass(const int* __restrict__ row, const int* __restrict__ col,
                             int* __restrict__ cursor, int* __restrict__ col_s,
                             int E, int r_lo, int r_hi) {
    int e = blockIdx.x * blockDim.x + threadIdx.x;
    if (e < E) {
        int r = row[e];
        if (r >= r_lo && r < r_hi) {
            int p = atomicAdd(&cursor[r], 1);
            col_s[p] = col[e];
        }
    }
}

// One row per wave: g=lane>>3 indexes 8 edges, li=lane&7 the 16B chunk.
// One gather instruction covers 8 edges x full 128B rows. Butterfly reduce
// over g; lanes g==0 apply -dinv[r]*two, subtract prev, store (and scaled).
__global__ __launch_bounds__(256) void spmm_row(
        const int* __restrict__ rowptr, const int* __restrict__ cols,
        const uint4* __restrict__ ins, const uint4* __restrict__ prevu,
        const float* __restrict__ dinv, float two,
        uint4* __restrict__ outu, uint4* __restrict__ outs, int n) {
    int lane = threadIdx.x & 63;
    int r = (blockIdx.x * blockDim.x + threadIdx.x) >> 6;
    if (r >= n) return;
    int g = lane >> 3, li = lane & 7;
    int s = rowptr[r], e = rowptr[r + 1];
    float acc[8];
#pragma unroll
    for (int j = 0; j < 8; ++j) acc[j] = 0.f;

    int p = s;
    for (; p + 16 <= e; p += 16) {               // 2 rounds in flight
        int c0 = cols[p + g];
        int c1 = cols[p + 8 + g];
        U16 v0, v1;
        v0.u = ins[(size_t)c0 * 8 + li];
        v1.u = ins[(size_t)c1 * 8 + li];
#pragma unroll
        for (int t = 0; t < 4; ++t) {
            float2 f0 = __half22float2(v0.h2[t]);
            float2 f1 = __half22float2(v1.h2[t]);
            acc[2 * t]     += f0.x + f1.x;
            acc[2 * t + 1] += f0.y + f1.y;
        }
    }
    for (; p + 8 <= e; p += 8) {
        int c0 = cols[p + g];
        U16 v0;
        v0.u = ins[(size_t)c0 * 8 + li];
#pragma unroll
        for (int t = 0; t < 4; ++t) {
            float2 f0 = __half22float2(v0.h2[t]);
            acc[2 * t]     += f0.x;
            acc[2 * t + 1] += f0.y;
        }
    }
    if (p + g < e) {                              // masked tail round
        int c0 = cols[p + g];
        U16 v0;
        v0.u = ins[(size_t)c0 * 8 + li];
#pragma unroll
        for (int t = 0; t < 4; ++t) {
            float2 f0 = __half22float2(v0.h2[t]);
            acc[2 * t]     += f0.x;
            acc[2 * t + 1] += f0.y;
        }
    }
    // butterfly reduce over g (lane bits 3..5)
#pragma unroll
    for (int j = 0; j < 8; ++j) {
        acc[j] += __shfl_xor(acc[j], 8, 64);
        acc[j] += __shfl_xor(acc[j], 16, 64);
        acc[j] += __shfl_xor(acc[j], 32, 64);
    }
    if (g == 0) {
        float d = dinv[r];
        float rs = -d * two;
        float res[8];
        if (prevu) {
            U16 pv;
            pv.u = prevu[(size_t)r * 8 + li];
#pragma unroll
            for (int t = 0; t < 4; ++t) {
                float2 f = __half22float2(pv.h2[t]);
                res[2 * t]     = fmaf(rs, acc[2 * t], -f.x);
                res[2 * t + 1] = fmaf(rs, acc[2 * t + 1], -f.y);
            }
        } else {
#pragma unroll
            for (int j = 0; j < 8; ++j) res[j] = rs * acc[j];
        }
        U16 ru;
#pragma unroll
        for (int t = 0; t < 4; ++t)
            ru.h2[t] = __float22half2_rn(make_float2(res[2 * t], res[2 * t + 1]));
        outu[(size_t)r * 8 + li] = ru.u;
        if (outs) {
            U16 rsv;
#pragma unroll
            for (int t = 0; t < 4; ++t)
                rsv.h2[t] = __float22half2_rn(make_float2(d * res[2 * t], d * res[2 * t + 1]));
            outs[(size_t)r * 8 + li] = rsv.u;
        }
    }
}

__device__ inline float tanh_fast(float x) {
    x = fmaxf(-10.f, fminf(10.f, x));
    float e = __expf(2.f * x);
    return (e - 1.f) / (e + 1.f);
}

// MFMA GEMM + tanh + final dot. Block = 256 thr = 4 waves; wave = 16 nodes x
// 128 h (8 tiles of 16x16, K=32/step, 8 steps over K=256). LDS-free.
__global__ __launch_bounds__(256) void gemm_mfma(
        const uint4* __restrict__ tx0, const uint4* __restrict__ tx1,
        const uint4* __restrict__ tx2, const uint4* __restrict__ tx3,
        const uint4* __restrict__ bfrag,
        const float* __restrict__ cheb_b, const float* __restrict__ fw,
        const float* __restrict__ fb, float* __restrict__ out, int n) {
    int tid = threadIdx.x;
    int lane = tid & 63;
    int wave = tid >> 6;
    int q = lane >> 4, m = lane & 15;
    int node_base = blockIdx.x * 64 + wave * 16;
    int node = node_base + m;
    size_t nd = (node < n) ? (size_t)node : 0;   // clamp; store is guarded

    f32x4 acc[8];
#pragma unroll
    for (int t = 0; t < 8; ++t) acc[t] = (f32x4){0.f, 0.f, 0.f, 0.f};

    const uint4* txs[4] = {tx0, tx1, tx2, tx3};
#pragma unroll
    for (int kk = 0; kk < 8; ++kk) {
        U16 av;
        av.u = txs[kk >> 1][nd * 8 + (kk & 1) * 4 + q];
#pragma unroll
        for (int ht = 0; ht < 8; ++ht) {
            U16 bv;
            bv.u = bfrag[(kk * 8 + ht) * 64 + lane];
            acc[ht] = __builtin_amdgcn_mfma_f32_16x16x32_f16(av.h8, bv.h8, acc[ht], 0, 0, 0);
        }
    }

    float s[4] = {0.f, 0.f, 0.f, 0.f};
#pragma unroll
    for (int ht = 0; ht < 8; ++ht) {
        int h = ht * 16 + m;
        float cb = cheb_b[h];
        float fv = fw[h];
#pragma unroll
        for (int r = 0; r < 4; ++r)
            s[r] = fmaf(tanh_fast(acc[ht][r] + cb), fv, s[r]);
    }
#pragma unroll
    for (int r = 0; r < 4; ++r) {
        for (int msk = 1; msk < 16; msk <<= 1)
            s[r] += __shfl_xor(s[r], msk, 64);
    }
    if (m == 0) {
        float fb0 = fb[0];
#pragma unroll
        for (int r = 0; r < 4; ++r) {
            int o = node_base + q * 4 + r;
            if (o < n) out[o] = s[r] + fb0;
        }
    }
}

extern "C" void kernel_launch(void* const* d_in, const int* in_sizes, int n_in,
                              void* d_out, int out_size, void* d_ws, size_t ws_size,
                              hipStream_t stream) {
    const float* features = (const float*)d_in[0];
    const int*   edge_index = (const int*)d_in[1];
    const float* cheb_w  = (const float*)d_in[2];
    const float* cheb_b  = (const float*)d_in[3];
    const float* final_w = (const float*)d_in[4];
    const float* final_b = (const float*)d_in[5];
    int N = in_sizes[0] / FIN;
    int E = in_sizes[1] / 2;
    const int* row = edge_index;        // edge_index[0, :]
    const int* col = edge_index + E;    // edge_index[1, :]

    char* p = (char*)d_ws;
    auto alloc = [&](size_t bytes) {
        char* r = p;
        p += (bytes + 255) & ~(size_t)255;
        return r;
    };
    int*   deg    = (int*)alloc((size_t)N * 4);
    float* dinv   = (float*)alloc((size_t)N * 4);
    int*   rowptr = (int*)alloc((size_t)(N + 1) * 4);
    int*   cursor = (int*)alloc((size_t)N * 4);
    int*   bsum   = (int*)alloc(1024 * 4);
    int*   col_s  = (int*)alloc((size_t)E * 4);
    uint4* feath  = (uint4*)alloc((size_t)N * FIN * 2);   // unscaled fp16
    uint4* feats  = (uint4*)alloc((size_t)N * FIN * 2);   // dinv-scaled fp16
    uint4* tx1h   = (uint4*)alloc((size_t)N * FIN * 2);
    uint4* tx1s   = (uint4*)alloc((size_t)N * FIN * 2);
    uint4* tx2h   = (uint4*)alloc((size_t)N * FIN * 2);
    uint4* tx2s   = (uint4*)alloc((size_t)N * FIN * 2);
    uint4* tx3h   = (uint4*)alloc((size_t)N * FIN * 2);
    uint4* bfrag  = (uint4*)alloc(4096 * 16);             // 64 KB B fragments

    hipMemsetAsync(deg, 0, (size_t)N * 4, stream);
    count_deg<<<(E + 255) / 256, 256, 0, stream>>>(row, deg, E);
    make_dinv<<<(N + 255) / 256, 256, 0, stream>>>(deg, dinv, N);
    int n8 = N * FIN / 8;
    cvt_feat<<<(n8 + 255) / 256, 256, 0, stream>>>((const float4*)features, dinv,
                                                   feath, feats, n8);
    make_bfrag<<<16, 256, 0, stream>>>(cheb_w, bfrag);
    int nb = (N + 1023) / 1024;
    scan_local<<<nb, 1024, 0, stream>>>(deg, rowptr, bsum, N);
    scan_bsums<<<1, 64, 0, stream>>>(bsum, nb);
    scan_finish<<<(N + 1 + 255) / 256, 256, 0, stream>>>(rowptr, bsum, cursor, N, E);

    // 4 sequential row-striped scatter passes (write locality)
    int eb = (E + 255) / 256;
    int stride = (N + 3) / 4;
    for (int pass = 0; pass < 4; ++pass) {
        int lo = pass * stride;
        int hi = (pass == 3) ? N : lo + stride;
        scatter_pass<<<eb, 256, 0, stream>>>(row, col, cursor, col_s, E, lo, hi);
    }

    int spmm_blocks = ((size_t)N * 64 + 255) / 256;   // one wave per row
    // Tx1 = L_hat @ x
    spmm_row<<<spmm_blocks, 256, 0, stream>>>(rowptr, col_s, feats, nullptr, dinv,
                                              1.f, tx1h, tx1s, N);
    // Tx2 = 2 * L_hat @ Tx1 - Tx0
    spmm_row<<<spmm_blocks, 256, 0, stream>>>(rowptr, col_s, tx1s, feath, dinv,
                                              2.f, tx2h, tx2s, N);
    // Tx3 = 2 * L_hat @ Tx2 - Tx1
    spmm_row<<<spmm_blocks, 256, 0, stream>>>(rowptr, col_s, tx2s, tx1h, dinv,
                                              2.f, tx3h, nullptr, N);

    gemm_mfma<<<(N + 63) / 64, 256, 0, stream>>>(feath, tx1h, tx2h, tx3h, bfrag,
                                                 cheb_b, final_w, final_b,
                                                 (float*)d_out, N);
}